// Round 4
// baseline (559.805 us; speedup 1.0000x reference)
//
#include <hip/hip_runtime.h>
#include <hip/hip_bf16.h>

#define P_CNT 16
#define J_CNT 23
#define VPT   4   // vertices per thread: amortizes the 1104 wave-uniform LDS reads

// Device-global scratch for the tiny pose stage -> vertex stage handoff.
__device__ float4 g_A[P_CNT * J_CNT * 3];   // per-(p,j) 3x4 skinning matrix rows
__device__ float  g_shift[P_CNT * 3];

struct PosePtrs { const float* p[11]; };

// One thread per pose (16 active). Builds g_A, g_shift, and output-1.
__global__ void pose_kernel(const float* __restrict__ joints,
                            const float* __restrict__ disp,
                            const float* __restrict__ rdis,
                            PosePtrs pp,
                            float* __restrict__ out1)    // [P][J][3]
{
    __shared__ float Gs[P_CNT][J_CNT][12];   // global transforms, affine rows [R|t]
    int p = threadIdx.x;
    if (p >= P_CNT) return;

    const int par[J_CNT]     = {-1,0,1,1,3,4,5,4,7,4,9,1,11,12,13,12,15,12,17,0,19,0,21};
    const int slot_of[J_CNT] = {0,-1,-1,1,2,3,-1,4,-1,5,-1,6,7,8,-1,9,-1,10,-1,-1,-1,-1,-1};
    const float slot_sc[11]  = {
        0.7853981633974483f, 1.5707963267948966f, 1.5707963267948966f, 0.7853981633974483f,
        0.7853981633974483f, 0.7853981633974483f, 1.5707963267948966f, 1.5707963267948966f,
        0.7853981633974483f, 0.7853981633974483f, 0.7853981633974483f};

    for (int j = 0; j < J_CNT; ++j) {
        float rx = 0.f, ry = 0.f, rz = 0.f;
        int s = slot_of[j];
        if (s >= 0) {
            float sc = slot_sc[s];
            rx = sc * tanhf(pp.p[s][p * 3 + 0]);
            ry = sc * tanhf(pp.p[s][p * 3 + 1]);
            rz = sc * tanhf(pp.p[s][p * 3 + 2]);
        }
        float ang = sqrtf(rx * rx + ry * ry + rz * rz + 1e-16f);
        float sn = sinf(ang), cs = cosf(ang);
        float C = 1.f - cs;
        float inva = 1.f / ang;
        float x = rx * inva, y = ry * inva, z = rz * inva;
        float R[3][3];
        R[0][0] = 1.f - C * (y * y + z * z); R[0][1] = -sn * z + C * x * y;       R[0][2] = sn * y + C * x * z;
        R[1][0] = sn * z + C * x * y;        R[1][1] = 1.f - C * (x * x + z * z); R[1][2] = -sn * x + C * y * z;
        R[2][0] = -sn * y + C * x * z;       R[2][1] = sn * x + C * y * z;        R[2][2] = 1.f - C * (x * x + y * y);

        int q = par[j];
        float t[3];
        for (int c = 0; c < 3; ++c) {
            float jc = joints[j * 3 + c];
            t[c] = (j == 0) ? jc : (jc - joints[q * 3 + c]);
        }
        if (j == 0) {
            for (int i = 0; i < 3; ++i) {
                Gs[p][0][i * 4 + 0] = R[i][0];
                Gs[p][0][i * 4 + 1] = R[i][1];
                Gs[p][0][i * 4 + 2] = R[i][2];
                Gs[p][0][i * 4 + 3] = t[i];
            }
        } else {
            for (int i = 0; i < 3; ++i) {
                float g0 = Gs[p][q][i * 4 + 0], g1 = Gs[p][q][i * 4 + 1];
                float g2 = Gs[p][q][i * 4 + 2], g3 = Gs[p][q][i * 4 + 3];
                Gs[p][j][i * 4 + 0] = g0 * R[0][0] + g1 * R[1][0] + g2 * R[2][0];
                Gs[p][j][i * 4 + 1] = g0 * R[0][1] + g1 * R[1][1] + g2 * R[2][1];
                Gs[p][j][i * 4 + 2] = g0 * R[0][2] + g1 * R[1][2] + g2 * R[2][2];
                Gs[p][j][i * 4 + 3] = g0 * t[0] + g1 * t[1] + g2 * t[2] + g3;
            }
        }
    }

    float sh[3];
    for (int c = 0; c < 3; ++c) {
        sh[c] = rdis[p * 3 + c] + 3.f * tanhf(disp[p * 3 + c]);
        g_shift[p * 3 + c] = sh[c];
    }

    for (int j = 0; j < J_CNT; ++j) {
        float jx = joints[j * 3 + 0];
        float jy = joints[j * 3 + 1];
        float jz = joints[j * 3 + 2];
        for (int i = 0; i < 3; ++i) {
            float g0 = Gs[p][j][i * 4 + 0], g1 = Gs[p][j][i * 4 + 1];
            float g2 = Gs[p][j][i * 4 + 2], g3 = Gs[p][j][i * 4 + 3];
            g_A[(p * J_CNT + j) * 3 + i] =
                make_float4(g0, g1, g2, g3 - (g0 * jx + g1 * jy + g2 * jz));
            out1[(p * J_CNT + j) * 3 + i] = g3 + sh[i];
        }
    }
}

// Each thread handles VPT vertices (strided by 64 within its wave) so the
// wave-uniform LDS reads of the A matrices are amortized VPT times.
__global__ __launch_bounds__(256) void lbs_vertex(
    const float* __restrict__ verts,     // [V][3]
    const float* __restrict__ weights,   // [V][23]
    float* __restrict__ out0,            // [P][V][3]
    int V)
{
    __shared__ float4 As[P_CNT * J_CNT * 3];   // 17.25 KB
    __shared__ float  sh[P_CNT * 3];
    for (int i = threadIdx.x; i < P_CNT * J_CNT * 3; i += 256) As[i] = g_A[i];
    for (int i = threadIdx.x; i < P_CNT * 3; i += 256) sh[i] = g_shift[i];
    __syncthreads();

    const int lane = threadIdx.x & 63;
    const int wv   = threadIdx.x >> 6;
    const long long vbase = (long long)blockIdx.x * (256 * VPT) + wv * (64 * VPT) + lane;

    long long vi[VPT];
    bool ok[VPT];
    float w[VPT][J_CNT];
    float X[VPT], Y[VPT], Z[VPT];
#pragma unroll
    for (int k = 0; k < VPT; ++k) {
        long long v = vbase + k * 64;
        ok[k] = (v < V);
        vi[k] = ok[k] ? v : (V - 1);
        const float* wr = weights + vi[k] * J_CNT;
#pragma unroll
        for (int j = 0; j < J_CNT; ++j) w[k][j] = wr[j];
        X[k] = verts[vi[k] * 3 + 0];
        Y[k] = verts[vi[k] * 3 + 1];
        Z[k] = verts[vi[k] * 3 + 2];
    }

#pragma unroll 1   // keep code size sane: pose loop stays a loop
    for (int p = 0; p < P_CNT; ++p) {
        float4 t0[VPT], t1[VPT], t2[VPT];
#pragma unroll
        for (int k = 0; k < VPT; ++k) {
            t0[k] = make_float4(0.f, 0.f, 0.f, 0.f);
            t1[k] = make_float4(0.f, 0.f, 0.f, 0.f);
            t2[k] = make_float4(0.f, 0.f, 0.f, 0.f);
        }
        const float4* Ap = As + p * (J_CNT * 3);
#pragma unroll
        for (int j = 0; j < J_CNT; ++j) {
            float4 a0 = Ap[j * 3 + 0], a1 = Ap[j * 3 + 1], a2 = Ap[j * 3 + 2];
#pragma unroll
            for (int k = 0; k < VPT; ++k) {
                float wj = w[k][j];
                t0[k].x = fmaf(wj, a0.x, t0[k].x); t0[k].y = fmaf(wj, a0.y, t0[k].y);
                t0[k].z = fmaf(wj, a0.z, t0[k].z); t0[k].w = fmaf(wj, a0.w, t0[k].w);
                t1[k].x = fmaf(wj, a1.x, t1[k].x); t1[k].y = fmaf(wj, a1.y, t1[k].y);
                t1[k].z = fmaf(wj, a1.z, t1[k].z); t1[k].w = fmaf(wj, a1.w, t1[k].w);
                t2[k].x = fmaf(wj, a2.x, t2[k].x); t2[k].y = fmaf(wj, a2.y, t2[k].y);
                t2[k].z = fmaf(wj, a2.z, t2[k].z); t2[k].w = fmaf(wj, a2.w, t2[k].w);
            }
        }
        float shx = sh[p * 3 + 0], shy = sh[p * 3 + 1], shz = sh[p * 3 + 2];
#pragma unroll
        for (int k = 0; k < VPT; ++k) {
            if (!ok[k]) continue;
            float ox = fmaf(t0[k].x, X[k], fmaf(t0[k].y, Y[k], fmaf(t0[k].z, Z[k], t0[k].w))) + shx;
            float oy = fmaf(t1[k].x, X[k], fmaf(t1[k].y, Y[k], fmaf(t1[k].z, Z[k], t1[k].w))) + shy;
            float oz = fmaf(t2[k].x, X[k], fmaf(t2[k].y, Y[k], fmaf(t2[k].z, Z[k], t2[k].w))) + shz;
            long long base = ((long long)p * V + vi[k]) * 3;
            out0[base + 0] = ox;
            out0[base + 1] = oy;
            out0[base + 2] = oz;
        }
    }
}

extern "C" void kernel_launch(void* const* d_in, const int* in_sizes, int n_in,
                              void* d_out, int out_size, void* d_ws, size_t ws_size,
                              hipStream_t stream) {
    const float* verts   = (const float*)d_in[0];  // (1,V,3)
    const float* joints  = (const float*)d_in[1];  // (1,23,3)
    const float* weights = (const float*)d_in[2];  // (V,23)
    const float* disp    = (const float*)d_in[3];  // (16,1,3)
    const float* rdis    = (const float*)d_in[4];  // (16,3)
    PosePtrs pp;
    for (int i = 0; i < 11; ++i) pp.p[i] = (const float*)d_in[5 + i];

    int V = in_sizes[0] / 3;  // 500000
    float* out0 = (float*)d_out;
    float* out1 = out0 + (long long)P_CNT * V * 3;

    pose_kernel<<<1, 64, 0, stream>>>(joints, disp, rdis, pp, out1);
    int G = (V + 256 * VPT - 1) / (256 * VPT);
    lbs_vertex<<<G, 256, 0, stream>>>(verts, weights, out0, V);
}

// Round 6
// 332.358 us; speedup vs baseline: 1.6843x; 1.6843x over previous
//
#include <hip/hip_runtime.h>
#include <hip/hip_bf16.h>

#define P_CNT 16
#define J_CNT 23
#define VPT   2   // vertices per thread; w[VPT][23] stays well under the VGPR cliff

// Device-global scratch for the pose->vertex handoff. NOT d_ws: the harness
// re-poisons d_ws around every timed launch, which raced with this handoff in
// round 5. Device globals are recomputed from restored inputs every call.
__device__ float4 g_A[P_CNT * J_CNT * 3];   // per-(p,j) 3x4 skinning matrix rows
__device__ float  g_shift[P_CNT * 3];

struct PosePtrs { const float* p[11]; };

// One thread per pose (16 active). Builds g_A, g_shift, and output-1.
__global__ void pose_kernel(const float* __restrict__ joints,
                            const float* __restrict__ disp,
                            const float* __restrict__ rdis,
                            PosePtrs pp,
                            float* __restrict__ out1)    // [P][J][3]
{
    __shared__ float Gs[P_CNT][J_CNT][12];   // global transforms, affine rows [R|t]
    int p = threadIdx.x;
    if (p >= P_CNT) return;

    const int par[J_CNT]     = {-1,0,1,1,3,4,5,4,7,4,9,1,11,12,13,12,15,12,17,0,19,0,21};
    const int slot_of[J_CNT] = {0,-1,-1,1,2,3,-1,4,-1,5,-1,6,7,8,-1,9,-1,10,-1,-1,-1,-1,-1};
    const float slot_sc[11]  = {
        0.7853981633974483f, 1.5707963267948966f, 1.5707963267948966f, 0.7853981633974483f,
        0.7853981633974483f, 0.7853981633974483f, 1.5707963267948966f, 1.5707963267948966f,
        0.7853981633974483f, 0.7853981633974483f, 0.7853981633974483f};

    for (int j = 0; j < J_CNT; ++j) {
        float rx = 0.f, ry = 0.f, rz = 0.f;
        int s = slot_of[j];
        if (s >= 0) {
            float sc = slot_sc[s];
            rx = sc * tanhf(pp.p[s][p * 3 + 0]);
            ry = sc * tanhf(pp.p[s][p * 3 + 1]);
            rz = sc * tanhf(pp.p[s][p * 3 + 2]);
        }
        float ang = sqrtf(rx * rx + ry * ry + rz * rz + 1e-16f);
        float sn = sinf(ang), cs = cosf(ang);
        float C = 1.f - cs;
        float inva = 1.f / ang;
        float x = rx * inva, y = ry * inva, z = rz * inva;
        float R[3][3];
        R[0][0] = 1.f - C * (y * y + z * z); R[0][1] = -sn * z + C * x * y;       R[0][2] = sn * y + C * x * z;
        R[1][0] = sn * z + C * x * y;        R[1][1] = 1.f - C * (x * x + z * z); R[1][2] = -sn * x + C * y * z;
        R[2][0] = -sn * y + C * x * z;       R[2][1] = sn * x + C * y * z;        R[2][2] = 1.f - C * (x * x + y * y);

        int q = par[j];
        float t[3];
        for (int c = 0; c < 3; ++c) {
            float jc = joints[j * 3 + c];
            t[c] = (j == 0) ? jc : (jc - joints[q * 3 + c]);
        }
        if (j == 0) {
            for (int i = 0; i < 3; ++i) {
                Gs[p][0][i * 4 + 0] = R[i][0];
                Gs[p][0][i * 4 + 1] = R[i][1];
                Gs[p][0][i * 4 + 2] = R[i][2];
                Gs[p][0][i * 4 + 3] = t[i];
            }
        } else {
            for (int i = 0; i < 3; ++i) {
                float g0 = Gs[p][q][i * 4 + 0], g1 = Gs[p][q][i * 4 + 1];
                float g2 = Gs[p][q][i * 4 + 2], g3 = Gs[p][q][i * 4 + 3];
                Gs[p][j][i * 4 + 0] = g0 * R[0][0] + g1 * R[1][0] + g2 * R[2][0];
                Gs[p][j][i * 4 + 1] = g0 * R[0][1] + g1 * R[1][1] + g2 * R[2][1];
                Gs[p][j][i * 4 + 2] = g0 * R[0][2] + g1 * R[1][2] + g2 * R[2][2];
                Gs[p][j][i * 4 + 3] = g0 * t[0] + g1 * t[1] + g2 * t[2] + g3;
            }
        }
    }

    float sh[3];
    for (int c = 0; c < 3; ++c) {
        sh[c] = rdis[p * 3 + c] + 3.f * tanhf(disp[p * 3 + c]);
        g_shift[p * 3 + c] = sh[c];
    }

    for (int j = 0; j < J_CNT; ++j) {
        float jx = joints[j * 3 + 0];
        float jy = joints[j * 3 + 1];
        float jz = joints[j * 3 + 2];
        for (int i = 0; i < 3; ++i) {
            float g0 = Gs[p][j][i * 4 + 0], g1 = Gs[p][j][i * 4 + 1];
            float g2 = Gs[p][j][i * 4 + 2], g3 = Gs[p][j][i * 4 + 3];
            g_A[(p * J_CNT + j) * 3 + i] =
                make_float4(g0, g1, g2, g3 - (g0 * jx + g1 * jy + g2 * jz));
            out1[(p * J_CNT + j) * 3 + i] = g3 + sh[i];
        }
    }
}

// Each thread handles VPT vertices (strided by 64 within its wave) so the 1104
// wave-uniform ds_read_b128 of the A matrices are amortized VPT times.
__global__ __launch_bounds__(256) void lbs_vertex(
    const float* __restrict__ verts,     // [V][3]
    const float* __restrict__ weights,   // [V][23]
    float* __restrict__ out0,            // [P][V][3]
    int V)
{
    __shared__ float4 As[P_CNT * J_CNT * 3];   // 17.25 KB
    __shared__ float  sh[P_CNT * 3];
    for (int i = threadIdx.x; i < P_CNT * J_CNT * 3; i += 256) As[i] = g_A[i];
    for (int i = threadIdx.x; i < P_CNT * 3; i += 256) sh[i] = g_shift[i];
    __syncthreads();

    const int lane = threadIdx.x & 63;
    const int wv   = threadIdx.x >> 6;
    const int vbase = blockIdx.x * (256 * VPT) + wv * (64 * VPT) + lane;

    int   vi[VPT];
    float w[VPT][J_CNT];
    float X[VPT], Y[VPT], Z[VPT];
#pragma unroll
    for (int k = 0; k < VPT; ++k) {
        int v = vbase + k * 64;
        vi[k] = (v < V) ? v : (V - 1);
        const float* wr = weights + (long long)vi[k] * J_CNT;
#pragma unroll
        for (int j = 0; j < J_CNT; ++j) w[k][j] = wr[j];
        X[k] = verts[(long long)vi[k] * 3 + 0];
        Y[k] = verts[(long long)vi[k] * 3 + 1];
        Z[k] = verts[(long long)vi[k] * 3 + 2];
    }

#pragma unroll 1   // keep the pose loop rolled: bounds code size & registers
    for (int p = 0; p < P_CNT; ++p) {
        float4 t0[VPT], t1[VPT], t2[VPT];
#pragma unroll
        for (int k = 0; k < VPT; ++k) {
            t0[k] = make_float4(0.f, 0.f, 0.f, 0.f);
            t1[k] = make_float4(0.f, 0.f, 0.f, 0.f);
            t2[k] = make_float4(0.f, 0.f, 0.f, 0.f);
        }
        const float4* Ap = As + p * (J_CNT * 3);
#pragma unroll
        for (int j = 0; j < J_CNT; ++j) {
            float4 a0 = Ap[j * 3 + 0], a1 = Ap[j * 3 + 1], a2 = Ap[j * 3 + 2];
#pragma unroll
            for (int k = 0; k < VPT; ++k) {
                float wj = w[k][j];
                t0[k].x = fmaf(wj, a0.x, t0[k].x); t0[k].y = fmaf(wj, a0.y, t0[k].y);
                t0[k].z = fmaf(wj, a0.z, t0[k].z); t0[k].w = fmaf(wj, a0.w, t0[k].w);
                t1[k].x = fmaf(wj, a1.x, t1[k].x); t1[k].y = fmaf(wj, a1.y, t1[k].y);
                t1[k].z = fmaf(wj, a1.z, t1[k].z); t1[k].w = fmaf(wj, a1.w, t1[k].w);
                t2[k].x = fmaf(wj, a2.x, t2[k].x); t2[k].y = fmaf(wj, a2.y, t2[k].y);
                t2[k].z = fmaf(wj, a2.z, t2[k].z); t2[k].w = fmaf(wj, a2.w, t2[k].w);
            }
        }
        float shx = sh[p * 3 + 0], shy = sh[p * 3 + 1], shz = sh[p * 3 + 2];
#pragma unroll
        for (int k = 0; k < VPT; ++k) {
            if (vbase + k * 64 >= V) continue;
            float ox = fmaf(t0[k].x, X[k], fmaf(t0[k].y, Y[k], fmaf(t0[k].z, Z[k], t0[k].w))) + shx;
            float oy = fmaf(t1[k].x, X[k], fmaf(t1[k].y, Y[k], fmaf(t1[k].z, Z[k], t1[k].w))) + shy;
            float oz = fmaf(t2[k].x, X[k], fmaf(t2[k].y, Y[k], fmaf(t2[k].z, Z[k], t2[k].w))) + shz;
            long long base = ((long long)p * V + vi[k]) * 3;
            out0[base + 0] = ox;
            out0[base + 1] = oy;
            out0[base + 2] = oz;
        }
    }
}

extern "C" void kernel_launch(void* const* d_in, const int* in_sizes, int n_in,
                              void* d_out, int out_size, void* d_ws, size_t ws_size,
                              hipStream_t stream) {
    const float* verts   = (const float*)d_in[0];  // (1,V,3)
    const float* joints  = (const float*)d_in[1];  // (1,23,3)
    const float* weights = (const float*)d_in[2];  // (V,23)
    const float* disp    = (const float*)d_in[3];  // (16,1,3)
    const float* rdis    = (const float*)d_in[4];  // (16,3)
    PosePtrs pp;
    for (int i = 0; i < 11; ++i) pp.p[i] = (const float*)d_in[5 + i];

    int V = in_sizes[0] / 3;  // 500000
    float* out0 = (float*)d_out;
    float* out1 = out0 + (long long)P_CNT * V * 3;

    pose_kernel<<<1, 64, 0, stream>>>(joints, disp, rdis, pp, out1);
    int G = (V + 256 * VPT - 1) / (256 * VPT);
    lbs_vertex<<<G, 256, 0, stream>>>(verts, weights, out0, V);
}